// Round 11
// baseline (461.786 us; speedup 1.0000x reference)
//
#include <hip/hip_runtime.h>

#define NNODES 100000
#define NEDGES 1600000
#define ET (NEDGES + NNODES)      // 1,700,000 incl. self loops
#define NBUCK 782                 // ceil(100000/128) buckets of 128 nodes
#define NEG 0.2f
#define BNEPS 1e-5f
#define EPB 4096                  // edges per block, bucket passes
#define NBLK_E ((ET + EPB - 1) / EPB)   // 416

typedef __attribute__((ext_vector_type(8))) short short8;
typedef __attribute__((ext_vector_type(4))) float floatx4;
typedef __attribute__((ext_vector_type(2))) float floatx2;

__device__ __forceinline__ unsigned short f2b(float x) {
    unsigned int u = __float_as_uint(x);
    u += 0x7fff + ((u >> 16) & 1);        // RNE
    return (unsigned short)(u >> 16);
}
__device__ __forceinline__ float b2f(unsigned short u) {
    return __uint_as_float(((unsigned int)u) << 16);
}
__device__ __forceinline__ float blo2f(unsigned int v) {
    return __uint_as_float(v << 16);
}
__device__ __forceinline__ float bhi2f(unsigned int v) {
    return __uint_as_float(v & 0xffff0000u);
}
__device__ __forceinline__ floatx2 u2f2(unsigned int v) {
    floatx2 r;
    r.x = __uint_as_float(v << 16);
    r.y = __uint_as_float(v & 0xffff0000u);
    return r;
}

// ---------------- edge decode (int32 vs int64 hedge) ----------------
__device__ __forceinline__ int edge_src(const int* ei, int e, int w64) {
    if (e >= NEDGES) return e - NEDGES;          // self loop
    return w64 ? ei[2 * e] : ei[e];
}
__device__ __forceinline__ int edge_dst(const int* ei, int e, int w64) {
    if (e >= NEDGES) return e - NEDGES;
    return w64 ? ei[2 * (NEDGES + e)] : ei[NEDGES + e];
}

// ---------------- prep: dtype detect + W transpose + scratch zeroing ----------------
__global__ void k_prep(const float* __restrict__ W1, const float* __restrict__ W2,
                       unsigned short* __restrict__ WT1, unsigned short* __restrict__ WT2,
                       const int* ei, int* flag, int* bcnt, int* done, float* bnstat) {
    int t = blockIdx.x * 256 + threadIdx.x;      // 16384 threads
    if (t < 800) bcnt[t] = 0;                    // blocks 0..3 cover bucket counts
    if (blockIdx.x == 4) {
        bnstat[threadIdx.x] = 0.f;
    } else if (blockIdx.x == 5) {
        bnstat[256 + threadIdx.x] = 0.f;
    }
    if (t == 0) *done = 0;
    if (t == 1) {
        int is64 = 1;
        for (int j = 1; j < 16; j += 2)
            if (ei[j] != 0) is64 = 0;
        *flag = is64;
    }
    int k = t >> 7, n = t & 127;
    WT1[n * 128 + k] = f2b(W1[t]);
    WT2[n * 128 + k] = f2b(W2[t]);
}

// ---------------- CSR build pass A: bucket histogram (+inline scan, last block) ----
__global__ __launch_bounds__(256) void k_bhist(const int* __restrict__ ei,
                                               const int* flag, int* bcnt,
                                               int* done, int* bbase, int* bcur) {
    __shared__ int lc[784];
    __shared__ int sh[256];
    __shared__ int lastf;
    int t = threadIdx.x;
    for (int i = t; i < NBUCK; i += 256) lc[i] = 0;
    __syncthreads();
    int w64 = *flag;
    int base = blockIdx.x * EPB;
    for (int j = 0; j < EPB / 512; j++) {
        int e = base + j * 512 + t * 2;          // 2 edges per thread
        if (e + 1 < NEDGES) {
            int d0, d1;
            if (w64) {
                int4 dv = *(const int4*)&ei[2 * (NEDGES + e)];
                d0 = dv.x; d1 = dv.z;
            } else {
                int2 dv = *(const int2*)&ei[NEDGES + e];
                d0 = dv.x; d1 = dv.y;
            }
            atomicAdd(&lc[d0 >> 7], 1);
            atomicAdd(&lc[d1 >> 7], 1);
        } else {
            for (int k = 0; k < 2; k++) {
                int ee = e + k;
                if (ee < ET) atomicAdd(&lc[edge_dst(ei, ee, w64) >> 7], 1);
            }
        }
    }
    __syncthreads();
    for (int i = t; i < NBUCK; i += 256)
        if (lc[i]) atomicAdd(&bcnt[i], lc[i]);
    __threadfence();
    __syncthreads();
    if (t == 0) lastf = (atomicAdd(done, 1) == gridDim.x - 1) ? 1 : 0;
    __syncthreads();
    if (!lastf) return;
    // inline 782-bucket exclusive scan (4 per thread)
    int vals[4], pre[4], sum = 0;
#pragma unroll
    for (int i = 0; i < 4; i++) {
        int id = t * 4 + i;
        int v = (id < NBUCK) ? atomicAdd(&bcnt[id], 0) : 0;
        pre[i] = sum; vals[i] = v; sum += v;
    }
    sh[t] = sum;
    __syncthreads();
    for (int off = 1; off < 256; off <<= 1) {
        int add = (t >= off) ? sh[t - off] : 0;
        __syncthreads();
        sh[t] += add;
        __syncthreads();
    }
    int excl = sh[t] - sum;
#pragma unroll
    for (int i = 0; i < 4; i++) {
        int id = t * 4 + i;
        if (id < NBUCK) { bbase[id] = excl + pre[i]; bcur[id] = excl + pre[i]; }
    }
    if (t == 255) bbase[NBUCK] = sh[255];
    (void)vals;
}

// ---------------- pass C: partition packed pairs into bucket regions ----------------
// pairs packed: (src << 7) | (dst & 127); src < 2^17
__global__ __launch_bounds__(256) void k_bscatter(const int* __restrict__ ei,
                                                  const int* flag, int* bcur,
                                                  int* __restrict__ pairs) {
    __shared__ int lc[784];
    __shared__ int lbase[784];
    int t = threadIdx.x;
    for (int i = t; i < NBUCK; i += 256) lc[i] = 0;
    __syncthreads();
    int w64 = *flag;
    int base = blockIdx.x * EPB;
    for (int j = 0; j < EPB / 512; j++) {
        int e = base + j * 512 + t * 2;
        if (e + 1 < NEDGES) {
            int d0, d1;
            if (w64) {
                int4 dv = *(const int4*)&ei[2 * (NEDGES + e)];
                d0 = dv.x; d1 = dv.z;
            } else {
                int2 dv = *(const int2*)&ei[NEDGES + e];
                d0 = dv.x; d1 = dv.y;
            }
            atomicAdd(&lc[d0 >> 7], 1);
            atomicAdd(&lc[d1 >> 7], 1);
        } else {
            for (int k = 0; k < 2; k++) {
                int ee = e + k;
                if (ee < ET) atomicAdd(&lc[edge_dst(ei, ee, w64) >> 7], 1);
            }
        }
    }
    __syncthreads();
    for (int i = t; i < NBUCK; i += 256)
        if (lc[i]) lbase[i] = atomicAdd(&bcur[i], lc[i]);
    __syncthreads();
    for (int j = 0; j < EPB / 512; j++) {
        int e = base + j * 512 + t * 2;
        if (e + 1 < NEDGES) {
            int s0, s1, d0, d1;
            if (w64) {
                int4 sv = *(const int4*)&ei[2 * e];
                int4 dv = *(const int4*)&ei[2 * (NEDGES + e)];
                s0 = sv.x; s1 = sv.z; d0 = dv.x; d1 = dv.z;
            } else {
                int2 sv = *(const int2*)&ei[e];
                int2 dv = *(const int2*)&ei[NEDGES + e];
                s0 = sv.x; s1 = sv.y; d0 = dv.x; d1 = dv.y;
            }
            int p0 = atomicAdd(&lbase[d0 >> 7], 1);
            pairs[p0] = (s0 << 7) | (d0 & 127);
            int p1 = atomicAdd(&lbase[d1 >> 7], 1);
            pairs[p1] = (s1 << 7) | (d1 & 127);
        } else {
            for (int k = 0; k < 2; k++) {
                int ee = e + k;
                if (ee < ET) {
                    int src = edge_src(ei, ee, w64);
                    int dst = edge_dst(ei, ee, w64);
                    int pos = atomicAdd(&lbase[dst >> 7], 1);
                    pairs[pos] = (src << 7) | (dst & 127);
                }
            }
        }
    }
}

// ---------------- pass D: per-bucket counting sort -> rowptr + srcs ----------------
__global__ __launch_bounds__(256) void k_bsort(const int* __restrict__ pairs,
                                               const int* __restrict__ bbase,
                                               int* __restrict__ rowptr,
                                               int* __restrict__ srcs) {
    __shared__ int ncnt[128];
    __shared__ int nbase[128];
    __shared__ int sscan[128];
    int b = blockIdx.x, t = threadIdx.x;
    if (t < 128) ncnt[t] = 0;
    __syncthreads();
    int s0 = bbase[b], s1 = bbase[b + 1];
    for (int i = s0 + t; i < s1; i += 256)
        atomicAdd(&ncnt[pairs[i] & 127], 1);
    __syncthreads();
    int v = (t < 128) ? ncnt[t] : 0;
    if (t < 128) sscan[t] = v;
    __syncthreads();
    for (int off = 1; off < 128; off <<= 1) {
        int add = (t < 128 && t >= off) ? sscan[t - off] : 0;
        __syncthreads();
        if (t < 128) sscan[t] += add;
        __syncthreads();
    }
    if (t < 128) {
        int excl = sscan[t] - v;
        nbase[t] = excl;
        int node = b * 128 + t;
        if (node <= NNODES) rowptr[node] = s0 + excl;
    }
    __syncthreads();
    if (t < 128) ncnt[t] = nbase[t];   // cursor
    __syncthreads();
    for (int i = s0 + t; i < s1; i += 256) {
        int pr = pairs[i];
        int off = atomicAdd(&ncnt[pr & 127], 1);
        srcs[s0 + off] = ((unsigned int)pr) >> 7;
    }
}

// ---------------- MFMA GEMM, 128-row tile (+BN/ELU on bf16 A) + fused scores --------
template<bool BN>
__global__ __launch_bounds__(256) void k_gemm(const void* __restrict__ Ain,
        const unsigned short* __restrict__ WTg,
        const float* __restrict__ sums, const float* __restrict__ sqs,
        const float* __restrict__ gamma, const float* __restrict__ beta,
        const float* __restrict__ a_s, const float* __restrict__ a_d,
        float* __restrict__ es, float* __restrict__ ed,
        unsigned short* __restrict__ hB, int n) {
    __shared__ unsigned short lA[128][136];
    __shared__ unsigned short lW[128][136];
    __shared__ float las[128], lad[128];
    __shared__ float lsc[128], lsh[128];
    int t = threadIdx.x;
    int row0 = blockIdx.x * 128;
    if (t < 128) { las[t] = a_s[t]; lad[t] = a_d[t]; }
    if (BN && t < 128) {
        float mu = sums[t] * (1.f / NNODES);
        float var = fmaxf(sqs[t] * (1.f / NNODES) - mu * mu, 0.f);
        float s = gamma[t] * rsqrtf(var + BNEPS);
        lsc[t] = s;
        lsh[t] = beta[t] - mu * s;
    }

    const uint4* wt4 = (const uint4*)WTg;
#pragma unroll
    for (int j = 0; j < 8; j++) {
        int idx = t + j * 256;
        *(uint4*)&lW[idx >> 4][(idx & 15) * 8] = wt4[idx];
    }
    if (BN) __syncthreads();   // lsc/lsh visible before A staging

    if (BN) {
        const uint4* Ab = (const uint4*)Ain;   // bf16 rows, 16 uint4 each
#pragma unroll
        for (int j = 0; j < 8; j++) {
            int idx = t + j * 256;             // 2048 uint4 = 128 rows
            int r = idx >> 4, seg = idx & 15;
            uint4 v = make_uint4(0, 0, 0, 0);
            if (row0 + r < n) v = Ab[(size_t)(row0 + r) * 16 + seg];
            float f[8];
            f[0] = blo2f(v.x); f[1] = bhi2f(v.x);
            f[2] = blo2f(v.y); f[3] = bhi2f(v.y);
            f[4] = blo2f(v.z); f[5] = bhi2f(v.z);
            f[6] = blo2f(v.w); f[7] = bhi2f(v.w);
            unsigned short us[8];
#pragma unroll
            for (int k = 0; k < 8; k++) {
                int c = seg * 8 + k;
                float z = fmaf(f[k], lsc[c], lsh[c]);
                z = z > 0.f ? z : __expf(z) - 1.f;
                us[k] = f2b(z);
            }
            ushort4 u0, u1;
            u0.x = us[0]; u0.y = us[1]; u0.z = us[2]; u0.w = us[3];
            u1.x = us[4]; u1.y = us[5]; u1.z = us[6]; u1.w = us[7];
            *(ushort4*)&lA[r][seg * 8] = u0;
            *(ushort4*)&lA[r][seg * 8 + 4] = u1;
        }
    } else {
        const float* Af = (const float*)Ain;
#pragma unroll
        for (int j = 0; j < 16; j++) {
            int idx = t + j * 256;             // 4096 float4 = 128 rows
            int r = idx >> 5, c4 = idx & 31;
            float4 v = make_float4(0.f, 0.f, 0.f, 0.f);
            if (row0 + r < n) v = ((const float4*)Af)[(size_t)(row0 + r) * 32 + c4];
            ushort4 u;
            u.x = f2b(v.x); u.y = f2b(v.y); u.z = f2b(v.z); u.w = f2b(v.w);
            *(ushort4*)&lA[r][c4 * 4] = u;
        }
    }
    __syncthreads();

    int w = t >> 6, lane = t & 63;
    int m = lane & 15, q = lane >> 4;
    int ar0 = w * 32 + m, ar1 = w * 32 + 16 + m;   // two 16-row tiles per wave
    floatx4 acc0[8], acc1[8];
#pragma unroll
    for (int ct = 0; ct < 8; ct++) { acc0[ct] = (floatx4)0.0f; acc1[ct] = (floatx4)0.0f; }

#pragma unroll
    for (int kt = 0; kt < 4; kt++) {
        int kb = kt * 32 + q * 8;
        short8 af0 = *(const short8*)&lA[ar0][kb];
        short8 af1 = *(const short8*)&lA[ar1][kb];
#pragma unroll
        for (int ct = 0; ct < 8; ct++) {
            short8 bf = *(const short8*)&lW[ct * 16 + m][kb];
            acc0[ct] = __builtin_amdgcn_mfma_f32_16x16x32_bf16(af0, bf, acc0[ct], 0, 0, 0);
            acc1[ct] = __builtin_amdgcn_mfma_f32_16x16x32_bf16(af1, bf, acc1[ct], 0, 0, 0);
        }
    }

    __syncthreads();   // all waves done with lA/lW as inputs
#pragma unroll
    for (int ct = 0; ct < 8; ct++)
#pragma unroll
        for (int r = 0; r < 4; r++) {
            lA[w * 32 + q * 4 + r][ct * 16 + m] = f2b(acc0[ct][r]);
            lA[w * 32 + 16 + q * 4 + r][ct * 16 + m] = f2b(acc1[ct][r]);
        }
    __syncthreads();
#pragma unroll
    for (int j = 0; j < 8; j++) {
        int idx = t + j * 256;                 // 2048 uint4 stores
        int r = idx >> 4, seg = idx & 15;
        int grow = row0 + r;
        if (grow < n) {
            uint4 v = *(const uint4*)&lA[r][seg * 8];
            ((uint4*)hB)[(size_t)grow * 16 + seg] = v;
        }
    }
    // fused attention scores: 2 threads per row, 64 chans each (dword LDS reads)
    int r = t >> 1, q2 = t & 1;
    float s1 = 0.f, s2 = 0.f;
#pragma unroll
    for (int k = 0; k < 32; k++) {
        int c = q2 * 64 + 2 * k;
        unsigned int u = *(const unsigned int*)&lA[r][c];
        float va = blo2f(u), vb = bhi2f(u);
        s1 += va * las[c] + vb * las[c + 1];
        s2 += va * lad[c] + vb * lad[c + 1];
    }
    s1 += __shfl_xor(s1, 1, 64);
    s2 += __shfl_xor(s2, 1, 64);
    if (q2 == 0 && row0 + r < n) { es[row0 + r] = s1; ed[row0 + r] = s2; }
}

// ---------------- fused softmax + weighted gather (half-wave per node) ----------
// one pass: no max subtraction (scores bounded |e| << 88, exp safe in fp32;
// alpha = p/den is shift-invariant so result identical)
// (src, p) pairs staged in a per-half-wave LDS row instead of shfl-broadcast.
// DIAGNOSTIC ROUND: launched as three node-range dispatches (~20 us each) so
// the rocprof top-5 exposes the never-measured mid-tier kernels (gemm, CSR
// build, outgemm). Blocks are per-node independent -> split is bit-exact.
__global__ __launch_bounds__(256) void k_attn(const unsigned short* __restrict__ hB,
                                              const int* __restrict__ srcs,
                                              const int* __restrict__ rowptr,
                                              const float* __restrict__ es,
                                              const float* __restrict__ ed,
                                              const float* __restrict__ bias,
                                              unsigned short* __restrict__ haggB,
                                              int node0, int nEnd) {
    __shared__ uint2 sp[8][32];                      // per half-wave (src, p) stage
    int w = node0 + ((blockIdx.x * 256 + threadIdx.x) >> 5);   // node per half-wave
    if (w >= nEnd) return;
    int hw = threadIdx.x >> 5;                       // half-wave slot in block
    int lane32 = threadIdx.x & 31;
    int g = lane32 >> 4, l16 = lane32 & 15;
    int start = rowptr[w], end = rowptr[w + 1];
    float edv = ed[w];
    const uint4* hp4 = (const uint4*)hB;
    floatx2 a0 = {0.f, 0.f}, a1 = {0.f, 0.f}, a2 = {0.f, 0.f}, a3 = {0.f, 0.f};
    float den = 0.f;

    for (int chunk = start; chunk < end; chunk += 32) {
        int i = chunk + lane32;
        int sv = 0; float pv = 0.f;
        if (i < end) {
            sv = srcs[i];
            float e = es[sv] + edv;
            e = e > 0.f ? e : NEG * e;
            pv = __expf(e);
            den += pv;
        }
        sp[hw][lane32] = make_uint2((unsigned)sv, __float_as_uint(pv));
        int cnt = min(32, end - chunk);
        for (int j = 0; j < cnt; j += 8) {           // group g: edges j+g, j+2+g, ...
            uint2 e0 = sp[hw][j + g];
            uint2 e1 = sp[hw][j + 2 + g];
            uint2 e2 = sp[hw][j + 4 + g];
            uint2 e3 = sp[hw][j + 6 + g];
            uint4 h0 = hp4[e0.x * 16u + l16];
            uint4 h1 = hp4[e1.x * 16u + l16];
            uint4 h2 = hp4[e2.x * 16u + l16];
            uint4 h3 = hp4[e3.x * 16u + l16];
            float p0 = __uint_as_float(e0.y), p1 = __uint_as_float(e1.y);
            float p2 = __uint_as_float(e2.y), p3 = __uint_as_float(e3.y);
            floatx2 P0 = {p0, p0};
            a0 += P0 * u2f2(h0.x); a1 += P0 * u2f2(h0.y);
            a2 += P0 * u2f2(h0.z); a3 += P0 * u2f2(h0.w);
            floatx2 P1 = {p1, p1};
            a0 += P1 * u2f2(h1.x); a1 += P1 * u2f2(h1.y);
            a2 += P1 * u2f2(h1.z); a3 += P1 * u2f2(h1.w);
            floatx2 P2 = {p2, p2};
            a0 += P2 * u2f2(h2.x); a1 += P2 * u2f2(h2.y);
            a2 += P2 * u2f2(h2.z); a3 += P2 * u2f2(h2.w);
            floatx2 P3 = {p3, p3};
            a0 += P3 * u2f2(h3.x); a1 += P3 * u2f2(h3.y);
            a2 += P3 * u2f2(h3.z); a3 += P3 * u2f2(h3.w);
        }
    }
    den += __shfl_xor(den, 1, 64);  den += __shfl_xor(den, 2, 64);
    den += __shfl_xor(den, 4, 64);  den += __shfl_xor(den, 8, 64);
    den += __shfl_xor(den, 16, 64);
    a0.x += __shfl_xor(a0.x, 16, 64); a0.y += __shfl_xor(a0.y, 16, 64);
    a1.x += __shfl_xor(a1.x, 16, 64); a1.y += __shfl_xor(a1.y, 16, 64);
    a2.x += __shfl_xor(a2.x, 16, 64); a2.y += __shfl_xor(a2.y, 16, 64);
    a3.x += __shfl_xor(a3.x, 16, 64); a3.y += __shfl_xor(a3.y, 16, 64);
    if (g == 0) {
        float inv = 1.f / den;                       // den > 0: self loop guaranteed
        const float2* b2p = (const float2*)bias;
        float2 c0 = b2p[l16 * 4 + 0], c1 = b2p[l16 * 4 + 1];
        float2 c2 = b2p[l16 * 4 + 2], c3 = b2p[l16 * 4 + 3];
        uint4 o;
        o.x = (unsigned int)f2b(fmaf(a0.x, inv, c0.x)) |
              ((unsigned int)f2b(fmaf(a0.y, inv, c0.y)) << 16);
        o.y = (unsigned int)f2b(fmaf(a1.x, inv, c1.x)) |
              ((unsigned int)f2b(fmaf(a1.y, inv, c1.y)) << 16);
        o.z = (unsigned int)f2b(fmaf(a2.x, inv, c2.x)) |
              ((unsigned int)f2b(fmaf(a2.y, inv, c2.y)) << 16);
        o.w = (unsigned int)f2b(fmaf(a3.x, inv, c3.x)) |
              ((unsigned int)f2b(fmaf(a3.y, inv, c3.y)) << 16);
        ((uint4*)haggB)[(size_t)w * 16 + l16] = o;
    }
}

// ---------------- BatchNorm stats from bf16 hagg ----------------
__global__ __launch_bounds__(256) void k_bnstats(const unsigned short* __restrict__ hin,
                                                 float* sums, float* sqs, int n) {
    __shared__ float red[4][256];
    int t = threadIdx.x;
    int c2 = t & 63, quarter = t >> 6;
    int r0 = blockIdx.x * 256;
    int rend = min(r0 + 256, n);
    const unsigned int* hp = (const unsigned int*)hin;
    float s0 = 0.f, q0 = 0.f, s1 = 0.f, q1 = 0.f;
    for (int r = r0 + quarter; r < rend; r += 4) {
        unsigned int v = hp[(size_t)r * 64 + c2];
        float a = blo2f(v), b = bhi2f(v);
        s0 += a; q0 += a * a;
        s1 += b; q1 += b * b;
    }
    *(float4*)&red[quarter][c2 * 4] = make_float4(s0, q0, s1, q1);
    __syncthreads();
    float v = red[0][t] + red[1][t] + red[2][t] + red[3][t];
    int c2i = t >> 2, k = t & 3;
    int ch = c2i * 2 + (k >> 1);
    if (k & 1) atomicAdd(&sqs[ch], v);
    else       atomicAdd(&sums[ch], v);
}

// ---------------- output head: wave-level k-split + scalar-pipe Wout ----------
// (unchanged from R10 -- current best known structure, ~43us; see R10 notes)
__global__ __launch_bounds__(256) void k_outgemm(const unsigned short* __restrict__ h,
                                                 const float* __restrict__ sums,
                                                 const float* __restrict__ sqs,
                                                 const float* __restrict__ gamma,
                                                 const float* __restrict__ beta,
                                                 const float* __restrict__ Wout,
                                                 const float* __restrict__ bout,
                                                 float* __restrict__ out, int n) {
    __shared__ float lsc[128], lsh[128];
    __shared__ float lacc[2][64][41];            // +1 pad word -> conflict-free
    int t = threadIdx.x;
    if (t < 128) {
        float mu = sums[t] * (1.f / NNODES);
        float var = fmaxf(sqs[t] * (1.f / NNODES) - mu * mu, 0.f);
        float s = gamma[t] * rsqrtf(var + BNEPS);
        lsc[t] = s;
        lsh[t] = beta[t] - mu * s;
    }
    __syncthreads();
    int wv = __builtin_amdgcn_readfirstlane(t >> 6);   // wave id, SGPR
    int lane = t & 63;
    int pairId = wv >> 1, jq = wv & 1;                 // both SGPR
    int row = blockIdx.x * 128 + pairId * 64 + lane;
    bool valid = row < n;
    const uint4* hb4 = (const uint4*)h;
    uint4 hreg[8];
#pragma unroll
    for (int s8 = 0; s8 < 8; s8++) {
        hreg[s8] = make_uint4(0, 0, 0, 0);
        if (valid) hreg[s8] = hb4[(size_t)row * 16 + jq * 8 + s8];
    }
    const float* wbase = Wout + jq * 64 * 40;          // SGPR base
    float acc[40];
#pragma unroll
    for (int j = 0; j < 40; j++) acc[j] = 0.f;
#pragma unroll
    for (int k8 = 0; k8 < 8; k8++) {
        uint4 v = hreg[k8];
        float f[8];
        f[0] = blo2f(v.x); f[1] = bhi2f(v.x);
        f[2] = blo2f(v.y); f[3] = bhi2f(v.y);
        f[4] = blo2f(v.z); f[5] = bhi2f(v.z);
        f[6] = blo2f(v.w); f[7] = bhi2f(v.w);
#pragma unroll
        for (int kk = 0; kk < 8; kk++) {
            int c = jq * 64 + k8 * 8 + kk;             // wave-uniform
            float z = fmaf(f[kk], lsc[c], lsh[c]);
            z = z > 0.f ? z : __expf(z) - 1.f;
            const float4* wr = (const float4*)(wbase + (k8 * 8 + kk) * 40);
#pragma unroll
            for (int j4 = 0; j4 < 10; j4++) {
                float4 wv4 = wr[j4];                   // s_load (uniform addr)
                acc[j4 * 4 + 0] = fmaf(z, wv4.x, acc[j4 * 4 + 0]);
                acc[j4 * 4 + 1] = fmaf(z, wv4.y, acc[j4 * 4 + 1]);
                acc[j4 * 4 + 2] = fmaf(z, wv4.z, acc[j4 * 4 + 2]);
                acc[j4 * 4 + 3] = fmaf(z, wv4.w, acc[j4 * 4 + 3]);
            }
        }
    }
    if (jq == 1) {
#pragma unroll
        for (int j = 0; j < 40; j++) lacc[pairId][lane][j] = acc[j];
    }
    __syncthreads();
    if (jq == 0 && valid) {
        const float4* b4 = (const float4*)bout;
        float4* outp = (float4*)(out + (size_t)row * 40);
#pragma unroll
        for (int j4 = 0; j4 < 10; j4++) {
            float4 bv = b4[j4];
            float4 o;
            o.x = acc[j4 * 4 + 0] + lacc[pairId][lane][j4 * 4 + 0] + bv.x;
            o.y = acc[j4 * 4 + 1] + lacc[pairId][lane][j4 * 4 + 1] + bv.y;
            o.z = acc[j4 * 4 + 2] + lacc[pairId][lane][j4 * 4 + 2] + bv.z;
            o.w = acc[j4 * 4 + 3] + lacc[pairId][lane][j4 * 4 + 3] + bv.w;
            outp[j4] = o;
        }
    }
}

// ---------------- launch ----------------
extern "C" void kernel_launch(void* const* d_in, const int* in_sizes, int n_in,
                              void* d_out, int out_size, void* d_ws, size_t ws_size,
                              hipStream_t stream) {
    const float* x      = (const float*)d_in[0];
    const int*   ei     = (const int*)d_in[1];
    const float* W1     = (const float*)d_in[2];
    const float* a_src1 = (const float*)d_in[3];
    const float* a_dst1 = (const float*)d_in[4];
    const float* b1     = (const float*)d_in[5];
    const float* W2     = (const float*)d_in[6];
    const float* a_src2 = (const float*)d_in[7];
    const float* a_dst2 = (const float*)d_in[8];
    const float* b2     = (const float*)d_in[9];
    const float* gamma  = (const float*)d_in[10];
    const float* beta   = (const float*)d_in[11];
    const float* Wout   = (const float*)d_in[12];
    const float* bout   = (const float*)d_in[13];
    float* out = (float*)d_out;

    char* p = (char*)d_ws;
    auto alloc = [&](size_t bytes) -> void* {
        void* r = (void*)p;
        p += (bytes + 255) & ~(size_t)255;
        return r;
    };
    unsigned short* hB    = (unsigned short*)alloc((size_t)NNODES * 128 * 2);
    unsigned short* haggB = (unsigned short*)alloc((size_t)NNODES * 128 * 2);
    float* es     = (float*)alloc((size_t)NNODES * 4);
    float* ed     = (float*)alloc((size_t)NNODES * 4);
    int*   pairs  = (int*)alloc((size_t)ET * 4);
    int*   srcs   = (int*)alloc((size_t)ET * 4);
    int*   rowptr = (int*)alloc((size_t)(NNODES + 1) * 4);
    int*   bcnt   = (int*)alloc(800 * 4);
    int*   bbase  = (int*)alloc(800 * 4);
    int*   bcur   = (int*)alloc(800 * 4);
    float* bnstat = (float*)alloc(4 * 128 * 4);
    unsigned short* WT1 = (unsigned short*)alloc(128 * 128 * 2);
    unsigned short* WT2 = (unsigned short*)alloc(128 * 128 * 2);
    int*   flag   = (int*)alloc(4);
    int*   done   = (int*)alloc(4);

    float* sum1 = bnstat, *sq1 = bnstat + 128, *sum2 = bnstat + 256, *sq2 = bnstat + 384;

    k_prep<<<64, 256, 0, stream>>>(W1, W2, WT1, WT2, ei, flag, bcnt, done, bnstat);
    k_bhist<<<NBLK_E, 256, 0, stream>>>(ei, flag, bcnt, done, bbase, bcur);
    k_bscatter<<<NBLK_E, 256, 0, stream>>>(ei, flag, bcur, pairs);
    k_bsort<<<NBUCK, 256, 0, stream>>>(pairs, bbase, rowptr, srcs);

    const int GB = (NNODES + 127) / 128;          // 782 (gemm tiles)
    const int SB = (NNODES + 255) / 256;          // 391
    const int OB = (NNODES + 127) / 128;          // 782 (128 rows per block, 4 waves)
    // 3-way attn split (diagnostic): ranges aligned to 8-node blocks
    const int NA = 33336, NB2 = 66672;
    const int A1 = NA / 8;                        // 4167
    const int A2 = (NB2 - NA) / 8;                // 4167
    const int A3 = (NNODES - NB2 + 7) / 8;        // 4166

    // ---- layer 1 ----
    k_gemm<false><<<GB, 256, 0, stream>>>(x, WT1, nullptr, nullptr, nullptr, nullptr,
                                          a_src1, a_dst1, es, ed, hB, NNODES);
    k_attn<<<A1, 256, 0, stream>>>(hB, srcs, rowptr, es, ed, b1, haggB, 0, NA);
    k_attn<<<A2, 256, 0, stream>>>(hB, srcs, rowptr, es, ed, b1, haggB, NA, NB2);
    k_attn<<<A3, 256, 0, stream>>>(hB, srcs, rowptr, es, ed, b1, haggB, NB2, NNODES);
    k_bnstats<<<SB, 256, 0, stream>>>(haggB, sum1, sq1, NNODES);

    // ---- layer 2 (BN+ELU finalized+fused in A-staging) ----
    k_gemm<true><<<GB, 256, 0, stream>>>(haggB, WT2, sum1, sq1, gamma, beta,
                                         a_src2, a_dst2, es, ed, hB, NNODES);
    k_attn<<<A1, 256, 0, stream>>>(hB, srcs, rowptr, es, ed, b2, haggB, 0, NA);
    k_attn<<<A2, 256, 0, stream>>>(hB, srcs, rowptr, es, ed, b2, haggB, NA, NB2);
    k_attn<<<A3, 256, 0, stream>>>(hB, srcs, rowptr, es, ed, b2, haggB, NB2, NNODES);
    k_bnstats<<<SB, 256, 0, stream>>>(haggB, sum2, sq2, NNODES);

    // ---- head (BN finalize + ELU fused into staging) ----
    k_outgemm<<<OB, 256, 0, stream>>>(haggB, sum2, sq2, gamma, beta, Wout, bout, out, NNODES);

    (void)in_sizes; (void)n_in; (void)out_size; (void)ws_size;
}

// Round 12
// 402.880 us; speedup vs baseline: 1.1462x; 1.1462x over previous
//
#include <hip/hip_runtime.h>

#define NNODES 100000
#define NEDGES 1600000
#define ET (NEDGES + NNODES)      // 1,700,000 incl. self loops
#define NBUCK 782                 // ceil(100000/128) buckets of 128 nodes
#define NEG 0.2f
#define BNEPS 1e-5f
#define EPB 4096                  // edges per block, bucket passes
#define NBLK_E ((ET + EPB - 1) / EPB)   // 416
#define CAP 4096                  // fixed bucket capacity (mean 2174, ~41 sigma)

typedef __attribute__((ext_vector_type(8))) short short8;
typedef __attribute__((ext_vector_type(4))) float floatx4;
typedef __attribute__((ext_vector_type(2))) float floatx2;

__device__ __forceinline__ unsigned short f2b(float x) {
    unsigned int u = __float_as_uint(x);
    u += 0x7fff + ((u >> 16) & 1);        // RNE
    return (unsigned short)(u >> 16);
}
__device__ __forceinline__ float b2f(unsigned short u) {
    return __uint_as_float(((unsigned int)u) << 16);
}
__device__ __forceinline__ float blo2f(unsigned int v) {
    return __uint_as_float(v << 16);
}
__device__ __forceinline__ float bhi2f(unsigned int v) {
    return __uint_as_float(v & 0xffff0000u);
}
__device__ __forceinline__ floatx2 u2f2(unsigned int v) {
    floatx2 r;
    r.x = __uint_as_float(v << 16);
    r.y = __uint_as_float(v & 0xffff0000u);
    return r;
}

// ---------------- edge decode (int32 vs int64 hedge) ----------------
__device__ __forceinline__ int edge_src(const int* ei, int e, int w64) {
    if (e >= NEDGES) return e - NEDGES;          // self loop
    return w64 ? ei[2 * e] : ei[e];
}
__device__ __forceinline__ int edge_dst(const int* ei, int e, int w64) {
    if (e >= NEDGES) return e - NEDGES;
    return w64 ? ei[2 * (NEDGES + e)] : ei[NEDGES + e];
}

// ---------------- prep: dtype detect + W transpose + bucket cursor init ----------
// bcur[b] = b*CAP replaces the whole k_bhist histogram+scan pass: buckets get
// fixed-capacity regions, so no global prefix sum is needed.
__global__ void k_prep(const float* __restrict__ W1, const float* __restrict__ W2,
                       unsigned short* __restrict__ WT1, unsigned short* __restrict__ WT2,
                       const int* ei, int* flag, int* bcur, float* bnstat) {
    int t = blockIdx.x * 256 + threadIdx.x;      // 16384 threads
    if (t < 800) bcur[t] = t * CAP;
    if (blockIdx.x == 4) {
        bnstat[threadIdx.x] = 0.f;
    } else if (blockIdx.x == 5) {
        bnstat[256 + threadIdx.x] = 0.f;
    }
    if (t == 1) {
        int is64 = 1;
        for (int j = 1; j < 16; j += 2)
            if (ei[j] != 0) is64 = 0;
        *flag = is64;
    }
    int k = t >> 7, n = t & 127;
    WT1[n * 128 + k] = f2b(W1[t]);
    WT2[n * 128 + k] = f2b(W2[t]);
}

// ---------------- scatter: partition packed pairs into fixed bucket regions ------
// pairs packed: (src << 7) | (dst & 127); src < 2^17. Block-local histogram ->
// one atomicAdd reservation per touched bucket -> scatter (same mechanics as
// before; only the cursor's initial value changed from scanned base to b*CAP).
__global__ __launch_bounds__(256) void k_bscatter(const int* __restrict__ ei,
                                                  const int* flag, int* bcur,
                                                  int* __restrict__ pairs) {
    __shared__ int lc[784];
    __shared__ int lbase[784];
    int t = threadIdx.x;
    for (int i = t; i < NBUCK; i += 256) lc[i] = 0;
    __syncthreads();
    int w64 = *flag;
    int base = blockIdx.x * EPB;
    for (int j = 0; j < EPB / 512; j++) {
        int e = base + j * 512 + t * 2;
        if (e + 1 < NEDGES) {
            int d0, d1;
            if (w64) {
                int4 dv = *(const int4*)&ei[2 * (NEDGES + e)];
                d0 = dv.x; d1 = dv.z;
            } else {
                int2 dv = *(const int2*)&ei[NEDGES + e];
                d0 = dv.x; d1 = dv.y;
            }
            atomicAdd(&lc[d0 >> 7], 1);
            atomicAdd(&lc[d1 >> 7], 1);
        } else {
            for (int k = 0; k < 2; k++) {
                int ee = e + k;
                if (ee < ET) atomicAdd(&lc[edge_dst(ei, ee, w64) >> 7], 1);
            }
        }
    }
    __syncthreads();
    for (int i = t; i < NBUCK; i += 256)
        if (lc[i]) lbase[i] = atomicAdd(&bcur[i], lc[i]);
    __syncthreads();
    for (int j = 0; j < EPB / 512; j++) {
        int e = base + j * 512 + t * 2;
        if (e + 1 < NEDGES) {
            int s0, s1, d0, d1;
            if (w64) {
                int4 sv = *(const int4*)&ei[2 * e];
                int4 dv = *(const int4*)&ei[2 * (NEDGES + e)];
                s0 = sv.x; s1 = sv.z; d0 = dv.x; d1 = dv.z;
            } else {
                int2 sv = *(const int2*)&ei[e];
                int2 dv = *(const int2*)&ei[NEDGES + e];
                s0 = sv.x; s1 = sv.y; d0 = dv.x; d1 = dv.y;
            }
            int p0 = atomicAdd(&lbase[d0 >> 7], 1);
            pairs[p0] = (s0 << 7) | (d0 & 127);
            int p1 = atomicAdd(&lbase[d1 >> 7], 1);
            pairs[p1] = (s1 << 7) | (d1 & 127);
        } else {
            for (int k = 0; k < 2; k++) {
                int ee = e + k;
                if (ee < ET) {
                    int src = edge_src(ei, ee, w64);
                    int dst = edge_dst(ei, ee, w64);
                    int pos = atomicAdd(&lbase[dst >> 7], 1);
                    pairs[pos] = (src << 7) | (dst & 127);
                }
            }
        }
    }
}

// ---------------- per-bucket counting sort -> rowse (start,end) + srcs ----------
__global__ __launch_bounds__(256) void k_bsort(const int* __restrict__ pairs,
                                               const int* __restrict__ bcur,
                                               int2* __restrict__ rowse,
                                               int* __restrict__ srcs) {
    __shared__ int ncnt[128];
    __shared__ int nbase[128];
    __shared__ int sscan[128];
    int b = blockIdx.x, t = threadIdx.x;
    if (t < 128) ncnt[t] = 0;
    __syncthreads();
    int s0 = b * CAP, s1 = bcur[b];
    for (int i = s0 + t; i < s1; i += 256)
        atomicAdd(&ncnt[pairs[i] & 127], 1);
    __syncthreads();
    int v = (t < 128) ? ncnt[t] : 0;
    if (t < 128) sscan[t] = v;
    __syncthreads();
    for (int off = 1; off < 128; off <<= 1) {
        int add = (t < 128 && t >= off) ? sscan[t - off] : 0;
        __syncthreads();
        if (t < 128) sscan[t] += add;
        __syncthreads();
    }
    if (t < 128) {
        int excl = sscan[t] - v;
        nbase[t] = excl;
        int node = b * 128 + t;
        if (node < NNODES) rowse[node] = make_int2(s0 + excl, s0 + excl + v);
    }
    __syncthreads();
    if (t < 128) ncnt[t] = nbase[t];   // cursor
    __syncthreads();
    for (int i = s0 + t; i < s1; i += 256) {
        int pr = pairs[i];
        int off = atomicAdd(&ncnt[pr & 127], 1);
        srcs[s0 + off] = ((unsigned int)pr) >> 7;
    }
}

// ---------------- MFMA GEMM, 128-row tile (+BN/ELU on bf16 A) + fused scores --------
template<bool BN>
__global__ __launch_bounds__(256) void k_gemm(const void* __restrict__ Ain,
        const unsigned short* __restrict__ WTg,
        const float* __restrict__ sums, const float* __restrict__ sqs,
        const float* __restrict__ gamma, const float* __restrict__ beta,
        const float* __restrict__ a_s, const float* __restrict__ a_d,
        float* __restrict__ es, float* __restrict__ ed,
        unsigned short* __restrict__ hB, int n) {
    __shared__ unsigned short lA[128][136];
    __shared__ unsigned short lW[128][136];
    __shared__ float las[128], lad[128];
    __shared__ float lsc[128], lsh[128];
    int t = threadIdx.x;
    int row0 = blockIdx.x * 128;
    if (t < 128) { las[t] = a_s[t]; lad[t] = a_d[t]; }
    if (BN && t < 128) {
        float mu = sums[t] * (1.f / NNODES);
        float var = fmaxf(sqs[t] * (1.f / NNODES) - mu * mu, 0.f);
        float s = gamma[t] * rsqrtf(var + BNEPS);
        lsc[t] = s;
        lsh[t] = beta[t] - mu * s;
    }

    const uint4* wt4 = (const uint4*)WTg;
#pragma unroll
    for (int j = 0; j < 8; j++) {
        int idx = t + j * 256;
        *(uint4*)&lW[idx >> 4][(idx & 15) * 8] = wt4[idx];
    }
    if (BN) __syncthreads();   // lsc/lsh visible before A staging

    if (BN) {
        const uint4* Ab = (const uint4*)Ain;   // bf16 rows, 16 uint4 each
#pragma unroll
        for (int j = 0; j < 8; j++) {
            int idx = t + j * 256;             // 2048 uint4 = 128 rows
            int r = idx >> 4, seg = idx & 15;
            uint4 v = make_uint4(0, 0, 0, 0);
            if (row0 + r < n) v = Ab[(size_t)(row0 + r) * 16 + seg];
            float f[8];
            f[0] = blo2f(v.x); f[1] = bhi2f(v.x);
            f[2] = blo2f(v.y); f[3] = bhi2f(v.y);
            f[4] = blo2f(v.z); f[5] = bhi2f(v.z);
            f[6] = blo2f(v.w); f[7] = bhi2f(v.w);
            unsigned short us[8];
#pragma unroll
            for (int k = 0; k < 8; k++) {
                int c = seg * 8 + k;
                float z = fmaf(f[k], lsc[c], lsh[c]);
                z = z > 0.f ? z : __expf(z) - 1.f;
                us[k] = f2b(z);
            }
            ushort4 u0, u1;
            u0.x = us[0]; u0.y = us[1]; u0.z = us[2]; u0.w = us[3];
            u1.x = us[4]; u1.y = us[5]; u1.z = us[6]; u1.w = us[7];
            *(ushort4*)&lA[r][seg * 8] = u0;
            *(ushort4*)&lA[r][seg * 8 + 4] = u1;
        }
    } else {
        const float* Af = (const float*)Ain;
#pragma unroll
        for (int j = 0; j < 16; j++) {
            int idx = t + j * 256;             // 4096 float4 = 128 rows
            int r = idx >> 5, c4 = idx & 31;
            float4 v = make_float4(0.f, 0.f, 0.f, 0.f);
            if (row0 + r < n) v = ((const float4*)Af)[(size_t)(row0 + r) * 32 + c4];
            ushort4 u;
            u.x = f2b(v.x); u.y = f2b(v.y); u.z = f2b(v.z); u.w = f2b(v.w);
            *(ushort4*)&lA[r][c4 * 4] = u;
        }
    }
    __syncthreads();

    int w = t >> 6, lane = t & 63;
    int m = lane & 15, q = lane >> 4;
    int ar0 = w * 32 + m, ar1 = w * 32 + 16 + m;   // two 16-row tiles per wave
    floatx4 acc0[8], acc1[8];
#pragma unroll
    for (int ct = 0; ct < 8; ct++) { acc0[ct] = (floatx4)0.0f; acc1[ct] = (floatx4)0.0f; }

#pragma unroll
    for (int kt = 0; kt < 4; kt++) {
        int kb = kt * 32 + q * 8;
        short8 af0 = *(const short8*)&lA[ar0][kb];
        short8 af1 = *(const short8*)&lA[ar1][kb];
#pragma unroll
        for (int ct = 0; ct < 8; ct++) {
            short8 bf = *(const short8*)&lW[ct * 16 + m][kb];
            acc0[ct] = __builtin_amdgcn_mfma_f32_16x16x32_bf16(af0, bf, acc0[ct], 0, 0, 0);
            acc1[ct] = __builtin_amdgcn_mfma_f32_16x16x32_bf16(af1, bf, acc1[ct], 0, 0, 0);
        }
    }

    __syncthreads();   // all waves done with lA/lW as inputs
#pragma unroll
    for (int ct = 0; ct < 8; ct++)
#pragma unroll
        for (int r = 0; r < 4; r++) {
            lA[w * 32 + q * 4 + r][ct * 16 + m] = f2b(acc0[ct][r]);
            lA[w * 32 + 16 + q * 4 + r][ct * 16 + m] = f2b(acc1[ct][r]);
        }
    __syncthreads();
#pragma unroll
    for (int j = 0; j < 8; j++) {
        int idx = t + j * 256;                 // 2048 uint4 stores
        int r = idx >> 4, seg = idx & 15;
        int grow = row0 + r;
        if (grow < n) {
            uint4 v = *(const uint4*)&lA[r][seg * 8];
            ((uint4*)hB)[(size_t)grow * 16 + seg] = v;
        }
    }
    // fused attention scores: 2 threads per row, 64 chans each (dword LDS reads)
    int r = t >> 1, q2 = t & 1;
    float s1 = 0.f, s2 = 0.f;
#pragma unroll
    for (int k = 0; k < 32; k++) {
        int c = q2 * 64 + 2 * k;
        unsigned int u = *(const unsigned int*)&lA[r][c];
        float va = blo2f(u), vb = bhi2f(u);
        s1 += va * las[c] + vb * las[c + 1];
        s2 += va * lad[c] + vb * lad[c + 1];
    }
    s1 += __shfl_xor(s1, 1, 64);
    s2 += __shfl_xor(s2, 1, 64);
    if (q2 == 0 && row0 + r < n) { es[row0 + r] = s1; ed[row0 + r] = s2; }
}

// ---------------- fused softmax + weighted gather (half-wave per node) ----------
// one pass: no max subtraction (scores bounded |e| << 88, exp safe in fp32;
// alpha = p/den is shift-invariant so result identical)
// (src, p) pairs staged in a per-half-wave LDS row instead of shfl-broadcast.
// Row ranges come from rowse (start,end) since bucket regions are now padded.
__global__ __launch_bounds__(256) void k_attn(const unsigned short* __restrict__ hB,
                                              const int* __restrict__ srcs,
                                              const int2* __restrict__ rowse,
                                              const float* __restrict__ es,
                                              const float* __restrict__ ed,
                                              const float* __restrict__ bias,
                                              unsigned short* __restrict__ haggB, int n) {
    __shared__ uint2 sp[8][32];                      // per half-wave (src, p) stage
    int w = (blockIdx.x * 256 + threadIdx.x) >> 5;   // node per half-wave
    if (w >= n) return;
    int hw = threadIdx.x >> 5;                       // half-wave slot in block
    int lane32 = threadIdx.x & 31;
    int g = lane32 >> 4, l16 = lane32 & 15;
    int2 se = rowse[w];
    int start = se.x, end = se.y;
    float edv = ed[w];
    const uint4* hp4 = (const uint4*)hB;
    floatx2 a0 = {0.f, 0.f}, a1 = {0.f, 0.f}, a2 = {0.f, 0.f}, a3 = {0.f, 0.f};
    float den = 0.f;

    for (int chunk = start; chunk < end; chunk += 32) {
        int i = chunk + lane32;
        int sv = 0; float pv = 0.f;
        if (i < end) {
            sv = srcs[i];
            float e = es[sv] + edv;
            e = e > 0.f ? e : NEG * e;
            pv = __expf(e);
            den += pv;
        }
        sp[hw][lane32] = make_uint2((unsigned)sv, __float_as_uint(pv));
        int cnt = min(32, end - chunk);
        for (int j = 0; j < cnt; j += 8) {           // group g: edges j+g, j+2+g, ...
            uint2 e0 = sp[hw][j + g];
            uint2 e1 = sp[hw][j + 2 + g];
            uint2 e2 = sp[hw][j + 4 + g];
            uint2 e3 = sp[hw][j + 6 + g];
            uint4 h0 = hp4[e0.x * 16u + l16];
            uint4 h1 = hp4[e1.x * 16u + l16];
            uint4 h2 = hp4[e2.x * 16u + l16];
            uint4 h3 = hp4[e3.x * 16u + l16];
            float p0 = __uint_as_float(e0.y), p1 = __uint_as_float(e1.y);
            float p2 = __uint_as_float(e2.y), p3 = __uint_as_float(e3.y);
            floatx2 P0 = {p0, p0};
            a0 += P0 * u2f2(h0.x); a1 += P0 * u2f2(h0.y);
            a2 += P0 * u2f2(h0.z); a3 += P0 * u2f2(h0.w);
            floatx2 P1 = {p1, p1};
            a0 += P1 * u2f2(h1.x); a1 += P1 * u2f2(h1.y);
            a2 += P1 * u2f2(h1.z); a3 += P1 * u2f2(h1.w);
            floatx2 P2 = {p2, p2};
            a0 += P2 * u2f2(h2.x); a1 += P2 * u2f2(h2.y);
            a2 += P2 * u2f2(h2.z); a3 += P2 * u2f2(h2.w);
            floatx2 P3 = {p3, p3};
            a0 += P3 * u2f2(h3.x); a1 += P3 * u2f2(h3.y);
            a2 += P3 * u2f2(h3.z); a3 += P3 * u2f2(h3.w);
        }
    }
    den += __shfl_xor(den, 1, 64);  den += __shfl_xor(den, 2, 64);
    den += __shfl_xor(den, 4, 64);  den += __shfl_xor(den, 8, 64);
    den += __shfl_xor(den, 16, 64);
    a0.x += __shfl_xor(a0.x, 16, 64); a0.y += __shfl_xor(a0.y, 16, 64);
    a1.x += __shfl_xor(a1.x, 16, 64); a1.y += __shfl_xor(a1.y, 16, 64);
    a2.x += __shfl_xor(a2.x, 16, 64); a2.y += __shfl_xor(a2.y, 16, 64);
    a3.x += __shfl_xor(a3.x, 16, 64); a3.y += __shfl_xor(a3.y, 16, 64);
    if (g == 0) {
        float inv = 1.f / den;                       // den > 0: self loop guaranteed
        const float2* b2p = (const float2*)bias;
        float2 c0 = b2p[l16 * 4 + 0], c1 = b2p[l16 * 4 + 1];
        float2 c2 = b2p[l16 * 4 + 2], c3 = b2p[l16 * 4 + 3];
        uint4 o;
        o.x = (unsigned int)f2b(fmaf(a0.x, inv, c0.x)) |
              ((unsigned int)f2b(fmaf(a0.y, inv, c0.y)) << 16);
        o.y = (unsigned int)f2b(fmaf(a1.x, inv, c1.x)) |
              ((unsigned int)f2b(fmaf(a1.y, inv, c1.y)) << 16);
        o.z = (unsigned int)f2b(fmaf(a2.x, inv, c2.x)) |
              ((unsigned int)f2b(fmaf(a2.y, inv, c2.y)) << 16);
        o.w = (unsigned int)f2b(fmaf(a3.x, inv, c3.x)) |
              ((unsigned int)f2b(fmaf(a3.y, inv, c3.y)) << 16);
        ((uint4*)haggB)[(size_t)w * 16 + l16] = o;
    }
}

// ---------------- BatchNorm stats from bf16 hagg ----------------
__global__ __launch_bounds__(256) void k_bnstats(const unsigned short* __restrict__ hin,
                                                 float* sums, float* sqs, int n) {
    __shared__ float red[4][256];
    int t = threadIdx.x;
    int c2 = t & 63, quarter = t >> 6;
    int r0 = blockIdx.x * 256;
    int rend = min(r0 + 256, n);
    const unsigned int* hp = (const unsigned int*)hin;
    float s0 = 0.f, q0 = 0.f, s1 = 0.f, q1 = 0.f;
    for (int r = r0 + quarter; r < rend; r += 4) {
        unsigned int v = hp[(size_t)r * 64 + c2];
        float a = blo2f(v), b = bhi2f(v);
        s0 += a; q0 += a * a;
        s1 += b; q1 += b * b;
    }
    *(float4*)&red[quarter][c2 * 4] = make_float4(s0, q0, s1, q1);
    __syncthreads();
    float v = red[0][t] + red[1][t] + red[2][t] + red[3][t];
    int c2i = t >> 2, k = t & 3;
    int ch = c2i * 2 + (k >> 1);
    if (k & 1) atomicAdd(&sqs[ch], v);
    else       atomicAdd(&sums[ch], v);
}

// ---------------- output head: wave-level k-split + scalar-pipe Wout ----------
// (unchanged from R10 -- current best known structure; see R10 notes)
__global__ __launch_bounds__(256) void k_outgemm(const unsigned short* __restrict__ h,
                                                 const float* __restrict__ sums,
                                                 const float* __restrict__ sqs,
                                                 const float* __restrict__ gamma,
                                                 const float* __restrict__ beta,
                                                 const float* __restrict__ Wout,
                                                 const float* __restrict__ bout,
                                                 float* __restrict__ out, int n) {
    __shared__ float lsc[128], lsh[128];
    __shared__ float lacc[2][64][41];            // +1 pad word -> conflict-free
    int t = threadIdx.x;
    if (t < 128) {
        float mu = sums[t] * (1.f / NNODES);
        float var = fmaxf(sqs[t] * (1.f / NNODES) - mu * mu, 0.f);
        float s = gamma[t] * rsqrtf(var + BNEPS);
        lsc[t] = s;
        lsh[t] = beta[t] - mu * s;
    }
    __syncthreads();
    int wv = __builtin_amdgcn_readfirstlane(t >> 6);   // wave id, SGPR
    int lane = t & 63;
    int pairId = wv >> 1, jq = wv & 1;                 // both SGPR
    int row = blockIdx.x * 128 + pairId * 64 + lane;
    bool valid = row < n;
    const uint4* hb4 = (const uint4*)h;
    uint4 hreg[8];
#pragma unroll
    for (int s8 = 0; s8 < 8; s8++) {
        hreg[s8] = make_uint4(0, 0, 0, 0);
        if (valid) hreg[s8] = hb4[(size_t)row * 16 + jq * 8 + s8];
    }
    const float* wbase = Wout + jq * 64 * 40;          // SGPR base
    float acc[40];
#pragma unroll
    for (int j = 0; j < 40; j++) acc[j] = 0.f;
#pragma unroll
    for (int k8 = 0; k8 < 8; k8++) {
        uint4 v = hreg[k8];
        float f[8];
        f[0] = blo2f(v.x); f[1] = bhi2f(v.x);
        f[2] = blo2f(v.y); f[3] = bhi2f(v.y);
        f[4] = blo2f(v.z); f[5] = bhi2f(v.z);
        f[6] = blo2f(v.w); f[7] = bhi2f(v.w);
#pragma unroll
        for (int kk = 0; kk < 8; kk++) {
            int c = jq * 64 + k8 * 8 + kk;             // wave-uniform
            float z = fmaf(f[kk], lsc[c], lsh[c]);
            z = z > 0.f ? z : __expf(z) - 1.f;
            const float4* wr = (const float4*)(wbase + (k8 * 8 + kk) * 40);
#pragma unroll
            for (int j4 = 0; j4 < 10; j4++) {
                float4 wv4 = wr[j4];                   // s_load (uniform addr)
                acc[j4 * 4 + 0] = fmaf(z, wv4.x, acc[j4 * 4 + 0]);
                acc[j4 * 4 + 1] = fmaf(z, wv4.y, acc[j4 * 4 + 1]);
                acc[j4 * 4 + 2] = fmaf(z, wv4.z, acc[j4 * 4 + 2]);
                acc[j4 * 4 + 3] = fmaf(z, wv4.w, acc[j4 * 4 + 3]);
            }
        }
    }
    if (jq == 1) {
#pragma unroll
        for (int j = 0; j < 40; j++) lacc[pairId][lane][j] = acc[j];
    }
    __syncthreads();
    if (jq == 0 && valid) {
        const float4* b4 = (const float4*)bout;
        float4* outp = (float4*)(out + (size_t)row * 40);
#pragma unroll
        for (int j4 = 0; j4 < 10; j4++) {
            float4 bv = b4[j4];
            float4 o;
            o.x = acc[j4 * 4 + 0] + lacc[pairId][lane][j4 * 4 + 0] + bv.x;
            o.y = acc[j4 * 4 + 1] + lacc[pairId][lane][j4 * 4 + 1] + bv.y;
            o.z = acc[j4 * 4 + 2] + lacc[pairId][lane][j4 * 4 + 2] + bv.z;
            o.w = acc[j4 * 4 + 3] + lacc[pairId][lane][j4 * 4 + 3] + bv.w;
            outp[j4] = o;
        }
    }
}

// ---------------- launch ----------------
extern "C" void kernel_launch(void* const* d_in, const int* in_sizes, int n_in,
                              void* d_out, int out_size, void* d_ws, size_t ws_size,
                              hipStream_t stream) {
    const float* x      = (const float*)d_in[0];
    const int*   ei     = (const int*)d_in[1];
    const float* W1     = (const float*)d_in[2];
    const float* a_src1 = (const float*)d_in[3];
    const float* a_dst1 = (const float*)d_in[4];
    const float* b1     = (const float*)d_in[5];
    const float* W2     = (const float*)d_in[6];
    const float* a_src2 = (const float*)d_in[7];
    const float* a_dst2 = (const float*)d_in[8];
    const float* b2     = (const float*)d_in[9];
    const float* gamma  = (const float*)d_in[10];
    const float* beta   = (const float*)d_in[11];
    const float* Wout   = (const float*)d_in[12];
    const float* bout   = (const float*)d_in[13];
    float* out = (float*)d_out;

    char* p = (char*)d_ws;
    auto alloc = [&](size_t bytes) -> void* {
        void* r = (void*)p;
        p += (bytes + 255) & ~(size_t)255;
        return r;
    };
    unsigned short* hB    = (unsigned short*)alloc((size_t)NNODES * 128 * 2);
    unsigned short* haggB = (unsigned short*)alloc((size_t)NNODES * 128 * 2);
    float* es     = (float*)alloc((size_t)NNODES * 4);
    float* ed     = (float*)alloc((size_t)NNODES * 4);
    int*   pairs  = (int*)alloc((size_t)NBUCK * CAP * 4);   // 12.8 MB padded
    int*   srcs   = (int*)alloc((size_t)NBUCK * CAP * 4);   // 12.8 MB padded
    int2*  rowse  = (int2*)alloc((size_t)NNODES * 8);
    int*   bcur   = (int*)alloc(800 * 4);
    float* bnstat = (float*)alloc(4 * 128 * 4);
    unsigned short* WT1 = (unsigned short*)alloc(128 * 128 * 2);
    unsigned short* WT2 = (unsigned short*)alloc(128 * 128 * 2);
    int*   flag   = (int*)alloc(4);

    float* sum1 = bnstat, *sq1 = bnstat + 128, *sum2 = bnstat + 256, *sq2 = bnstat + 384;

    k_prep<<<64, 256, 0, stream>>>(W1, W2, WT1, WT2, ei, flag, bcur, bnstat);
    k_bscatter<<<NBLK_E, 256, 0, stream>>>(ei, flag, bcur, pairs);
    k_bsort<<<NBUCK, 256, 0, stream>>>(pairs, bcur, rowse, srcs);

    const int GB = (NNODES + 127) / 128;          // 782 (gemm tiles)
    const int AB = NNODES / 8;                    // 12500 (8 nodes/block, exact)
    const int SB = (NNODES + 255) / 256;          // 391
    const int OB = (NNODES + 127) / 128;          // 782 (128 rows per block, 4 waves)

    // ---- layer 1 ----
    k_gemm<false><<<GB, 256, 0, stream>>>(x, WT1, nullptr, nullptr, nullptr, nullptr,
                                          a_src1, a_dst1, es, ed, hB, NNODES);
    k_attn<<<AB, 256, 0, stream>>>(hB, srcs, rowse, es, ed, b1, haggB, NNODES);
    k_bnstats<<<SB, 256, 0, stream>>>(haggB, sum1, sq1, NNODES);

    // ---- layer 2 (BN+ELU finalized+fused in A-staging) ----
    k_gemm<true><<<GB, 256, 0, stream>>>(haggB, WT2, sum1, sq1, gamma, beta,
                                         a_src2, a_dst2, es, ed, hB, NNODES);
    k_attn<<<AB, 256, 0, stream>>>(hB, srcs, rowse, es, ed, b2, haggB, NNODES);
    k_bnstats<<<SB, 256, 0, stream>>>(haggB, sum2, sq2, NNODES);

    // ---- head (BN finalize + ELU fused into staging) ----
    k_outgemm<<<OB, 256, 0, stream>>>(haggB, sum2, sq2, gamma, beta, Wout, bout, out, NNODES);

    (void)in_sizes; (void)n_in; (void)out_size; (void)ws_size;
}